// Round 1
// baseline (191.161 us; speedup 1.0000x reference)
//
#include <hip/hip_runtime.h>

// Problem constants
static constexpr int NQ    = 12;
static constexpr int DEPTH = 4;
static constexpr int LAT   = 512;
static constexpr int FAST  = DEPTH * NQ;   // 48
static constexpr float DECAY = 0.9f;

// State layout: amplitude index i = lane*64 + r  (i bit 11..6 = lane bits 5..0,
// i bits 5..0 = register index r). Wire w <-> index bit (11-w).
//   w in [0,5]  -> lane bit (5-w)   : gate needs cross-lane shuffle
//   w in [6,11] -> register bit (11-w): gate is pure register op

template<int W>
__device__ __forceinline__ void apply_ry(float (&v)[64], int lane, float theta) {
    float h = 0.5f * theta;
    float c = __cosf(h);
    float s = __sinf(h);
    if constexpr (W >= 6) {
        constexpr int S = 1 << (11 - W);
        #pragma unroll
        for (int r0 = 0; r0 < 64; r0++) {
            if ((r0 & S) == 0) {
                float a = v[r0];
                float b = v[r0 + S];
                v[r0]     = c * a - s * b;
                v[r0 + S] = s * a + c * b;
            }
        }
    } else {
        constexpr int M = 1 << (5 - W);
        // my bit = (lane & M); new = c*v + (bit ? +s : -s) * partner
        float t = (lane & M) ? s : -s;
        #pragma unroll
        for (int r = 0; r < 64; r++) {
            float p = __shfl_xor(v[r], M, 64);
            v[r] = c * v[r] + t * p;
        }
    }
}

// CNOT with control wire W, target wire W+1 (adjacent).
// control bit = index bit (11-W), target bit = index bit (10-W).
template<int W>
__device__ __forceinline__ void apply_cnot(float (&v)[64], int lane) {
    if constexpr (W <= 4) {
        // both bits in lane index
        constexpr int CB = 1 << (5 - W);
        constexpr int TB = 1 << (4 - W);
        bool ctl = (lane & CB) != 0;
        #pragma unroll
        for (int r = 0; r < 64; r++) {
            float p = __shfl_xor(v[r], TB, 64);
            v[r] = ctl ? p : v[r];
        }
    } else if constexpr (W == 5) {
        // control = lane bit 0, target = register bit 5
        bool ctl = (lane & 1) != 0;
        #pragma unroll
        for (int r0 = 0; r0 < 32; r0++) {
            float a = v[r0];
            float b = v[r0 + 32];
            v[r0]      = ctl ? b : a;
            v[r0 + 32] = ctl ? a : b;
        }
    } else {
        // both bits in register index: compile-time register permutation
        constexpr int CBS = 1 << (11 - W);
        constexpr int TBS = 1 << (10 - W);
        #pragma unroll
        for (int r = 0; r < 64; r++) {
            if ((r & CBS) != 0 && (r & TBS) == 0) {
                float tmp = v[r];
                v[r]       = v[r | TBS];
                v[r | TBS] = tmp;
            }
        }
    }
}

template<int W>
__device__ __forceinline__ void init_rys(float (&v)[64], int lane, const float (&xa)[12]) {
    if constexpr (W < 12) {
        apply_ry<W>(v, lane, xa[W]);
        init_rys<W + 1>(v, lane, xa);
    }
}

template<int W>
__device__ __forceinline__ void cnot_chain(float (&v)[64], int lane) {
    if constexpr (W < 11) {
        apply_cnot<W>(v, lane);
        cnot_chain<W + 1>(v, lane);
    }
}

template<int W>
__device__ __forceinline__ void layer_rys(float (&v)[64], int lane, const float* ang) {
    if constexpr (W < 12) {
        apply_ry<W>(v, lane, ang[W]);   // LDS broadcast read, uniform across lanes
        layer_rys<W + 1>(v, lane, ang);
    }
}

__global__ __launch_bounds__(256, 2)
void fwp_kernel(const float* __restrict__ x_t,
                const float* __restrict__ fast_prev,
                const float* __restrict__ W_enc,
                const float* __restrict__ b_enc,
                const float* __restrict__ W_upd,
                const float* __restrict__ b_upd,
                const float* __restrict__ W_ro,
                const float* __restrict__ b_ro,
                float* __restrict__ out_y,
                float* __restrict__ out_fast) {
    const int lane = threadIdx.x & 63;
    const int wv   = threadIdx.x >> 6;
    const int b    = blockIdx.x * 4 + wv;   // one wave per batch element

    __shared__ float s_ang[4][FAST];

    // ---- load this row's x and broadcast to all lanes ----
    float xr = (lane < NQ) ? x_t[b * NQ + lane] : 0.0f;
    float xa[12];
    #pragma unroll
    for (int k = 0; k < 12; k++) xa[k] = __shfl(xr, k, 64);

    // ---- fused encoder (tanh GEMV) + update GEMV ----
    // lane handles latent j = lane + 64*t, t = 0..7; 48 partial accumulators
    float acc[FAST];
    #pragma unroll
    for (int o = 0; o < FAST; o++) acc[o] = 0.0f;

    #pragma unroll
    for (int t = 0; t < LAT / 64; t++) {
        int j = lane + 64 * t;
        float sum = b_enc[j];
        #pragma unroll
        for (int k = 0; k < 12; k++) sum += xa[k] * W_enc[j * 12 + k];
        float lv = tanhf(sum);
        #pragma unroll
        for (int o = 0; o < FAST; o++) acc[o] += lv * W_upd[o * LAT + j];
    }

    // butterfly-reduce each of the 48 partials across the wave; add bias,
    // decay the previous fast weights
    #pragma unroll
    for (int o = 0; o < FAST; o++) {
        float a = acc[o];
        #pragma unroll
        for (int m = 32; m >= 1; m >>= 1) a += __shfl_xor(a, m, 64);
        acc[o] = DECAY * fast_prev[b * FAST + o] + (a + b_upd[o]);
    }

    // stash angles in LDS (enables dynamic per-layer indexing + coalesced store)
    if (lane == 0) {
        #pragma unroll
        for (int o = 0; o < FAST; o++) s_ang[wv][o] = acc[o];
    }
    __syncthreads();

    if (lane < FAST) out_fast[b * FAST + lane] = s_ang[wv][lane];

    // ---- quantum circuit: 4096 real amplitudes in 64 VGPRs/lane ----
    float v[64];
    #pragma unroll
    for (int r = 0; r < 64; r++) v[r] = 0.015625f;   // 2^-6 uniform superposition

    init_rys<0>(v, lane, xa);

    #pragma unroll 1   // keep rolled: bounds code size / I-cache
    for (int layer = 0; layer < DEPTH; layer++) {
        cnot_chain<0>(v, lane);
        layer_rys<0>(v, lane, &s_ang[wv][layer * NQ]);
    }

    // ---- Z expectation per wire: <Z_w> = sum_i (+/-) |amp_i|^2 ----
    float tot = 0.0f;
    float pw[6];
    #pragma unroll
    for (int k = 0; k < 6; k++) pw[k] = 0.0f;
    #pragma unroll
    for (int r = 0; r < 64; r++) {
        float p = v[r] * v[r];
        tot += p;
        #pragma unroll
        for (int k = 0; k < 6; k++)             // wire w=6+k -> r bit (5-k)
            pw[k] += ((r >> (5 - k)) & 1) ? -p : p;
    }

    float zw[12];
    #pragma unroll
    for (int w = 0; w < 6; w++)                 // wire w -> lane bit (5-w)
        zw[w] = ((lane >> (5 - w)) & 1) ? -tot : tot;
    #pragma unroll
    for (int k = 0; k < 6; k++) zw[6 + k] = pw[k];

    #pragma unroll
    for (int w = 0; w < 12; w++) {
        float a = zw[w];
        #pragma unroll
        for (int m = 32; m >= 1; m >>= 1) a += __shfl_xor(a, m, 64);
        zw[w] = a;
    }

    // ---- readout: y = q_out . W_ro + b_ro ----
    if (lane == 0) {
        float y = b_ro[0];
        #pragma unroll
        for (int w = 0; w < 12; w++) y += W_ro[w] * zw[w];
        out_y[b] = y;
    }
}

extern "C" void kernel_launch(void* const* d_in, const int* in_sizes, int n_in,
                              void* d_out, int out_size, void* d_ws, size_t ws_size,
                              hipStream_t stream) {
    const float* x_t       = (const float*)d_in[0];
    const float* fast_prev = (const float*)d_in[1];
    const float* W_enc     = (const float*)d_in[2];
    const float* b_enc     = (const float*)d_in[3];
    const float* W_upd     = (const float*)d_in[4];
    const float* b_upd     = (const float*)d_in[5];
    const float* W_ro      = (const float*)d_in[6];
    const float* b_ro      = (const float*)d_in[7];
    float* out = (float*)d_out;

    // 2048 batch rows, one wave each, 4 waves per block
    fwp_kernel<<<2048 / 4, 256, 0, stream>>>(x_t, fast_prev, W_enc, b_enc,
                                             W_upd, b_upd, W_ro, b_ro,
                                             out /*y: [0,2048)*/,
                                             out + 2048 /*fast_next*/);
}

// Round 2
// 137.416 us; speedup vs baseline: 1.3911x; 1.3911x over previous
//
#include <hip/hip_runtime.h>

// Problem constants
static constexpr int NQ    = 12;
static constexpr int DEPTH = 4;
static constexpr int LAT   = 512;
static constexpr int FAST  = DEPTH * NQ;   // 48
static constexpr float DECAY = 0.9f;

// State layout: amplitude index i = lane*64 + r.
// Wire w <-> index bit (11-w):
//   w in [0,5]  -> lane bit (5-w)
//   w in [6,11] -> register bit (11-w)

template<int W>
__device__ __forceinline__ void apply_ry(float (&v)[64], int lane, float theta) {
    float h = 0.5f * theta;
    float c = __cosf(h);
    float s = __sinf(h);
    if constexpr (W >= 6) {
        constexpr int S = 1 << (11 - W);
        #pragma unroll
        for (int r0 = 0; r0 < 64; r0++) {
            if ((r0 & S) == 0) {
                float a = v[r0];
                float b = v[r0 + S];
                v[r0]     = c * a - s * b;
                v[r0 + S] = s * a + c * b;
            }
        }
    } else {
        constexpr int M = 1 << (5 - W);
        float t = (lane & M) ? s : -s;
        #pragma unroll
        for (int r = 0; r < 64; r++) {
            float p = __shfl_xor(v[r], M, 64);
            v[r] = c * v[r] + t * p;
        }
    }
}

// Register-bit CNOTs (w = 6..10): compile-time register permutation, ~free.
template<int W>
__device__ __forceinline__ void apply_cnot_reg(float (&v)[64]) {
    constexpr int CBS = 1 << (11 - W);
    constexpr int TBS = 1 << (10 - W);
    #pragma unroll
    for (int r = 0; r < 64; r++) {
        if ((r & CBS) != 0 && (r & TBS) == 0) {
            float tmp = v[r];
            v[r]       = v[r | TBS];
            v[r | TBS] = tmp;
        }
    }
}

template<int W>
__device__ __forceinline__ void cnot_reg_chain(float (&v)[64]) {
    if constexpr (W < 11) {
        apply_cnot_reg<W>(v);
        cnot_reg_chain<W + 1>(v);
    }
}

template<int W>
__device__ __forceinline__ void layer_rys(float (&v)[64], int lane, const float* ang) {
    if constexpr (W < 12) {
        apply_ry<W>(v, lane, ang[W]);
        layer_rys<W + 1>(v, lane, ang);
    }
}

__global__ __launch_bounds__(256, 2)
void fwp_kernel(const float* __restrict__ x_t,
                const float* __restrict__ fast_prev,
                const float* __restrict__ W_enc,
                const float* __restrict__ b_enc,
                const float* __restrict__ W_upd,
                const float* __restrict__ b_upd,
                const float* __restrict__ W_ro,
                const float* __restrict__ b_ro,
                float* __restrict__ out_y,
                float* __restrict__ out_fast) {
    const int lane = threadIdx.x & 63;
    const int wv   = threadIdx.x >> 6;
    const int b    = blockIdx.x * 4 + wv;   // one wave per batch row

    __shared__ float s_lat[4][LAT];   // 8 KB: per-wave latent vector
    __shared__ float s_ang[4][FAST];  // per-wave angles

    // ---- load this row's x and broadcast to all lanes ----
    float xr = (lane < NQ) ? x_t[b * NQ + lane] : 0.0f;
    float xa[NQ];
    #pragma unroll
    for (int k = 0; k < NQ; k++) xa[k] = __shfl(xr, k, 64);

    // ---- Phase A: latent = tanh(W_enc @ x + b_enc), 8 outputs per lane ----
    #pragma unroll
    for (int t = 0; t < LAT / 64; t++) {
        int j = lane + 64 * t;
        const float4* wr = (const float4*)(W_enc + j * NQ);  // 48B rows, 16B aligned
        float4 a0 = wr[0], a1 = wr[1], a2 = wr[2];
        float sum = b_enc[j]
            + a0.x * xa[0] + a0.y * xa[1] + a0.z * xa[2]  + a0.w * xa[3]
            + a1.x * xa[4] + a1.y * xa[5] + a1.z * xa[6]  + a1.w * xa[7]
            + a2.x * xa[8] + a2.y * xa[9] + a2.z * xa[10] + a2.w * xa[11];
        s_lat[wv][j] = tanhf(sum);
    }
    __syncthreads();

    // ---- Phase B: angles; lane o<48 owns one output row of W_upd ----
    if (lane < FAST) {
        const float4* wr = (const float4*)(W_upd + lane * LAT);  // 2KB rows
        const float4* lr = (const float4*)(s_lat[wv]);
        float sum = b_upd[lane];
        #pragma unroll 16
        for (int j = 0; j < LAT / 4; j++) {
            float4 w4 = wr[j];
            float4 l4 = lr[j];   // broadcast LDS read
            sum += w4.x * l4.x + w4.y * l4.y + w4.z * l4.z + w4.w * l4.w;
        }
        float ang = DECAY * fast_prev[b * FAST + lane] + sum;
        s_ang[wv][lane] = ang;
        out_fast[b * FAST + lane] = ang;
    }
    __syncthreads();

    // ---- closed-form init: 12 RYs on uniform state = product state ----
    // amp(i) = prod_w g_w(bit_w(i)), g(0)=(c-s)/sqrt2, g(1)=(c+s)/sqrt2
    float g0[NQ], g1[NQ];
    #pragma unroll
    for (int w = 0; w < NQ; w++) {
        float h = 0.5f * xa[w];
        float c = __cosf(h), s = __sinf(h);
        g0[w] = (c - s) * 0.70710678118654752f;
        g1[w] = (c + s) * 0.70710678118654752f;
    }
    float L = 1.0f;
    #pragma unroll
    for (int w = 0; w < 6; w++)
        L *= ((lane >> (5 - w)) & 1) ? g1[w] : g0[w];

    float v[64];
    v[0] = L;
    #pragma unroll
    for (int w = 6; w < NQ; w++) {
        const int S = 1 << (11 - w);       // 32,16,8,4,2,1
        #pragma unroll
        for (int r = 0; r < 64; r += 2 * S) {
            v[r + S] = v[r] * g1[w];
            v[r]     = v[r] * g0[w];
        }
    }

    // ---- precompute the composed lane permutation for CNOT(0..4) ----
    // gather: new[l] = old[sigma0(sigma1(...sigma4(l)))]
    int csrc = lane;
    #pragma unroll
    for (int w = 4; w >= 0; w--)
        csrc ^= ((csrc >> (5 - w)) & 1) << (4 - w);

    // ---- 4 layers: [CNOT chain 0..10] then 12 RYs ----
    #pragma unroll 1   // keep rolled: I-cache
    for (int layer = 0; layer < DEPTH; layer++) {
        // CNOT(0,1)..(4,5): one bpermute per register
        #pragma unroll
        for (int r = 0; r < 64; r++) v[r] = __shfl(v[r], csrc, 64);
        // CNOT(5,6): control = lane bit0, target = register bit5
        bool c5 = (lane & 1) != 0;
        #pragma unroll
        for (int r0 = 0; r0 < 32; r0++) {
            float a = v[r0], bb = v[r0 + 32];
            v[r0]      = c5 ? bb : a;
            v[r0 + 32] = c5 ? a : bb;
        }
        // CNOT(6,7)..(10,11): register renames, ~free
        cnot_reg_chain<6>(v);
        // 12 RYs with this layer's angles (LDS broadcast)
        layer_rys<0>(v, lane, &s_ang[wv][layer * NQ]);
    }

    // ---- Z expectations, folded directly into the readout dot ----
    float tot = 0.0f, pw[6] = {0, 0, 0, 0, 0, 0};
    #pragma unroll
    for (int r = 0; r < 64; r++) {
        float p = v[r] * v[r];
        tot += p;
        pw[0] += (r & 32) ? -p : p;   // wire 6
        pw[1] += (r & 16) ? -p : p;   // wire 7
        pw[2] += (r & 8)  ? -p : p;   // wire 8
        pw[3] += (r & 4)  ? -p : p;   // wire 9
        pw[4] += (r & 2)  ? -p : p;   // wire 10
        pw[5] += (r & 1)  ? -p : p;   // wire 11
    }
    float sl = 0.0f;
    #pragma unroll
    for (int w = 0; w < 6; w++) {
        float c = W_ro[w];
        sl += ((lane >> (5 - w)) & 1) ? -c : c;
    }
    float y = sl * tot;
    #pragma unroll
    for (int k = 0; k < 6; k++) y += W_ro[6 + k] * pw[k];
    #pragma unroll
    for (int m = 32; m >= 1; m >>= 1) y += __shfl_xor(y, m, 64);
    if (lane == 0) out_y[b] = y + b_ro[0];
}

extern "C" void kernel_launch(void* const* d_in, const int* in_sizes, int n_in,
                              void* d_out, int out_size, void* d_ws, size_t ws_size,
                              hipStream_t stream) {
    const float* x_t       = (const float*)d_in[0];
    const float* fast_prev = (const float*)d_in[1];
    const float* W_enc     = (const float*)d_in[2];
    const float* b_enc     = (const float*)d_in[3];
    const float* W_upd     = (const float*)d_in[4];
    const float* b_upd     = (const float*)d_in[5];
    const float* W_ro      = (const float*)d_in[6];
    const float* b_ro      = (const float*)d_in[7];
    float* out = (float*)d_out;

    fwp_kernel<<<2048 / 4, 256, 0, stream>>>(x_t, fast_prev, W_enc, b_enc,
                                             W_upd, b_upd, W_ro, b_ro,
                                             out /*y*/, out + 2048 /*fast_next*/);
}

// Round 3
// 126.341 us; speedup vs baseline: 1.5131x; 1.0877x over previous
//
#include <hip/hip_runtime.h>

// Problem constants
static constexpr int NQ    = 12;
static constexpr int DEPTH = 4;
static constexpr int LAT   = 512;
static constexpr int FAST  = DEPTH * NQ;   // 48
static constexpr float DECAY = 0.9f;

// State layout: amplitude index i = lane*64 + r.
// Wire w <-> index bit (11-w):
//   w in [0,5]  -> lane bit (5-w)
//   w in [6,11] -> register bit (11-w)

__device__ __forceinline__ float i2f(int x) { return __int_as_float(x); }

// VALU-pipe lane-XOR partner fetch (no LDS traffic except fallbacks).
template<int M>
__device__ __forceinline__ float xpartner(float x, int lane) {
    int xi = __float_as_int(x);
    if constexpr (M == 1) {        // quad_perm [1,0,3,2]
        return i2f(__builtin_amdgcn_update_dpp(xi, xi, 0xB1, 0xF, 0xF, true));
    } else if constexpr (M == 2) { // quad_perm [2,3,0,1]
        return i2f(__builtin_amdgcn_update_dpp(xi, xi, 0x4E, 0xF, 0xF, true));
    } else if constexpr (M == 4) { // xor7 (row_half_mirror) then xor3 (quad reverse)
        int t = __builtin_amdgcn_update_dpp(xi, xi, 0x141, 0xF, 0xF, true);
        return i2f(__builtin_amdgcn_update_dpp(t, t, 0x1B, 0xF, 0xF, true));
    } else if constexpr (M == 8) { // row_ror:8 == xor8 within 16-lane rows
        return i2f(__builtin_amdgcn_update_dpp(xi, xi, 0x128, 0xF, 0xF, true));
    } else if constexpr (M == 16) {
#if __has_builtin(__builtin_amdgcn_permlane16_swap)
        // With a==b==v the result pair holds {own, partner} at every lane,
        // whichever row-parity convention HW uses: partner = r0^r1^own.
        auto r = __builtin_amdgcn_permlane16_swap((unsigned)xi, (unsigned)xi, false, false);
        return i2f((int)(r[0] ^ r[1]) ^ xi);
#else
        return __shfl_xor(x, 16, 64);
#endif
    } else {
#if __has_builtin(__builtin_amdgcn_permlane32_swap)
        auto r = __builtin_amdgcn_permlane32_swap((unsigned)xi, (unsigned)xi, false, false);
        return i2f((int)(r[0] ^ r[1]) ^ xi);
#else
        return __shfl_xor(x, 32, 64);
#endif
    }
}

// RY on a lane wire (w in [0,5]) via VALU lane permutes.
template<int W>
__device__ __forceinline__ void ry_lane(float (&v)[64], int lane, float c, float s) {
    constexpr int M = 1 << (5 - W);
    float t = (lane & M) ? s : -s;
    #pragma unroll
    for (int r = 0; r < 64; r++) {
        float p = xpartner<M>(v[r], lane);
        v[r] = c * v[r] + t * p;
    }
}

// RY on a register wire (w in [6,11]): pure register butterflies.
template<int W>
__device__ __forceinline__ void ry_reg(float (&v)[64], float c, float s) {
    constexpr int S = 1 << (11 - W);
    #pragma unroll
    for (int r0 = 0; r0 < 64; r0++) {
        if ((r0 & S) == 0) {
            float a = v[r0];
            float b = v[r0 + S];
            v[r0]     = c * a - s * b;
            v[r0 + S] = s * a + c * b;
        }
    }
}

// Register-bit CNOTs (w = 6..10): compile-time register renames, ~free.
template<int W>
__device__ __forceinline__ void apply_cnot_reg(float (&v)[64]) {
    constexpr int CBS = 1 << (11 - W);
    constexpr int TBS = 1 << (10 - W);
    #pragma unroll
    for (int r = 0; r < 64; r++) {
        if ((r & CBS) != 0 && (r & TBS) == 0) {
            float tmp = v[r];
            v[r]       = v[r | TBS];
            v[r | TBS] = tmp;
        }
    }
}

template<int W>
__device__ __forceinline__ void cnot_reg_chain(float (&v)[64]) {
    if constexpr (W < 11) {
        apply_cnot_reg<W>(v);
        cnot_reg_chain<W + 1>(v);
    }
}

template<int W>
__device__ __forceinline__ void layer_rys(float (&v)[64], int lane, const float* ang) {
    if constexpr (W < 12) {
        float h = 0.5f * ang[W];
        float c = __cosf(h), s = __sinf(h);
        if constexpr (W < 6) ry_lane<W>(v, lane, c, s);
        else                 ry_reg<W>(v, c, s);
        layer_rys<W + 1>(v, lane, ang);
    }
}

__global__ __launch_bounds__(256, 2)
void fwp_kernel(const float* __restrict__ x_t,
                const float* __restrict__ fast_prev,
                const float* __restrict__ W_enc,
                const float* __restrict__ b_enc,
                const float* __restrict__ W_upd,
                const float* __restrict__ b_upd,
                const float* __restrict__ W_ro,
                const float* __restrict__ b_ro,
                float* __restrict__ out_y,
                float* __restrict__ out_fast) {
    const int lane = threadIdx.x & 63;
    const int wv   = threadIdx.x >> 6;
    const int b    = blockIdx.x * 4 + wv;   // one wave per batch row

    __shared__ float s_lat[4][LAT];   // 8 KB: per-wave latent vector
    __shared__ float s_ang[4][FAST];  // per-wave angles

    // ---- load this row's x and broadcast to all lanes ----
    float xr = (lane < NQ) ? x_t[b * NQ + lane] : 0.0f;
    float xa[NQ];
    #pragma unroll
    for (int k = 0; k < NQ; k++) xa[k] = __shfl(xr, k, 64);

    // ---- Phase A: latent = tanh(W_enc @ x + b_enc), 8 outputs per lane ----
    #pragma unroll
    for (int t = 0; t < LAT / 64; t++) {
        int j = lane + 64 * t;
        const float4* wr = (const float4*)(W_enc + j * NQ);
        float4 a0 = wr[0], a1 = wr[1], a2 = wr[2];
        float sum = b_enc[j]
            + a0.x * xa[0] + a0.y * xa[1] + a0.z * xa[2]  + a0.w * xa[3]
            + a1.x * xa[4] + a1.y * xa[5] + a1.z * xa[6]  + a1.w * xa[7]
            + a2.x * xa[8] + a2.y * xa[9] + a2.z * xa[10] + a2.w * xa[11];
        s_lat[wv][j] = tanhf(sum);
    }
    __syncthreads();

    // ---- Phase B: angles; lane o<48 owns one output row of W_upd ----
    if (lane < FAST) {
        const float4* wr = (const float4*)(W_upd + lane * LAT);
        const float4* lr = (const float4*)(s_lat[wv]);
        float sum = b_upd[lane];
        #pragma unroll 16
        for (int j = 0; j < LAT / 4; j++) {
            float4 w4 = wr[j];
            float4 l4 = lr[j];
            sum += w4.x * l4.x + w4.y * l4.y + w4.z * l4.z + w4.w * l4.w;
        }
        float ang = DECAY * fast_prev[b * FAST + lane] + sum;
        s_ang[wv][lane] = ang;
        out_fast[b * FAST + lane] = ang;
    }
    __syncthreads();

    // ---- closed-form init: 12 RYs on uniform state = product state ----
    float g0[NQ], g1[NQ];
    #pragma unroll
    for (int w = 0; w < NQ; w++) {
        float h = 0.5f * xa[w];
        float c = __cosf(h), s = __sinf(h);
        g0[w] = (c - s) * 0.70710678118654752f;
        g1[w] = (c + s) * 0.70710678118654752f;
    }
    float L = 1.0f;
    #pragma unroll
    for (int w = 0; w < 6; w++)
        L *= ((lane >> (5 - w)) & 1) ? g1[w] : g0[w];

    float v[64];
    v[0] = L;
    #pragma unroll
    for (int w = 6; w < NQ; w++) {
        const int S = 1 << (11 - w);
        #pragma unroll
        for (int r = 0; r < 64; r += 2 * S) {
            v[r + S] = v[r] * g1[w];
            v[r]     = v[r] * g0[w];
        }
    }

    // ---- composed lane permutation for CNOT(0..4): one bpermute per reg ----
    int csrc = lane;
    #pragma unroll
    for (int w = 4; w >= 0; w--)
        csrc ^= ((csrc >> (5 - w)) & 1) << (4 - w);
    const int csrc4 = csrc << 2;   // byte address for ds_bpermute

    // ---- 4 layers ----
    #pragma unroll 1
    for (int layer = 0; layer < DEPTH; layer++) {
        // CNOT(0,1)..(4,5): single composed lane gather (LDS pipe, overlaps VALU)
        #pragma unroll
        for (int r = 0; r < 64; r++)
            v[r] = i2f(__builtin_amdgcn_ds_bpermute(csrc4, __float_as_int(v[r])));
        // CNOT(5,6): control = lane bit0, target = register bit5
        bool c5 = (lane & 1) != 0;
        #pragma unroll
        for (int r0 = 0; r0 < 32; r0++) {
            float a = v[r0], bb = v[r0 + 32];
            v[r0]      = c5 ? bb : a;
            v[r0 + 32] = c5 ? a : bb;
        }
        // CNOT(6,7)..(10,11): register renames, free
        cnot_reg_chain<6>(v);
        // 12 RYs (lane wires via DPP/permlane on the VALU pipe)
        layer_rys<0>(v, lane, &s_ang[wv][layer * NQ]);
    }

    // ---- Z expectations folded into readout dot ----
    float tot = 0.0f, pw[6] = {0, 0, 0, 0, 0, 0};
    #pragma unroll
    for (int r = 0; r < 64; r++) {
        float p = v[r] * v[r];
        tot += p;
        pw[0] += (r & 32) ? -p : p;
        pw[1] += (r & 16) ? -p : p;
        pw[2] += (r & 8)  ? -p : p;
        pw[3] += (r & 4)  ? -p : p;
        pw[4] += (r & 2)  ? -p : p;
        pw[5] += (r & 1)  ? -p : p;
    }
    float sl = 0.0f;
    #pragma unroll
    for (int w = 0; w < 6; w++) {
        float c = W_ro[w];
        sl += ((lane >> (5 - w)) & 1) ? -c : c;
    }
    float y = sl * tot;
    #pragma unroll
    for (int k = 0; k < 6; k++) y += W_ro[6 + k] * pw[k];
    #pragma unroll
    for (int m = 32; m >= 1; m >>= 1) y += __shfl_xor(y, m, 64);
    if (lane == 0) out_y[b] = y + b_ro[0];
}

extern "C" void kernel_launch(void* const* d_in, const int* in_sizes, int n_in,
                              void* d_out, int out_size, void* d_ws, size_t ws_size,
                              hipStream_t stream) {
    const float* x_t       = (const float*)d_in[0];
    const float* fast_prev = (const float*)d_in[1];
    const float* W_enc     = (const float*)d_in[2];
    const float* b_enc     = (const float*)d_in[3];
    const float* W_upd     = (const float*)d_in[4];
    const float* b_upd     = (const float*)d_in[5];
    const float* W_ro      = (const float*)d_in[6];
    const float* b_ro      = (const float*)d_in[7];
    float* out = (float*)d_out;

    fwp_kernel<<<2048 / 4, 256, 0, stream>>>(x_t, fast_prev, W_enc, b_enc,
                                             W_upd, b_upd, W_ro, b_ro,
                                             out /*y*/, out + 2048 /*fast_next*/);
}